// Round 3
// baseline (720.452 us; speedup 1.0000x reference)
//
#include <hip/hip_runtime.h>

// ---------------------------------------------------------------------------
// SelfAttention (GN -> QKV 1x1 -> softmax(QK^T/16)V -> proj 1x1 + residual)
// B=8, C=256, GROUPS=32, H=W=64 -> T=4096. fp32 in/out, bf16 MFMA internally.
//
// R3: attention = R1 compute structure (measured 191.7 us, vs R2 238.6) +
//   - register software-pipelined K/V staging (global_load_dwordx4 -> VGPR ->
//     ds_write_b128), K prefetch issued after B2, V after B3, consumed at the
//     next loop-top ds_write: each barrier's vmcnt(0) drain now waits on loads
//     issued a full compute-phase earlier (L2 latency hidden).
//   - separate p_lds: 4 -> 3 barriers per tile.
// ---------------------------------------------------------------------------

typedef unsigned short u16;
typedef __attribute__((ext_vector_type(8))) short short8;   // 8 bf16 = 4 VGPR
typedef __attribute__((ext_vector_type(4))) float f32x4;    // 16x16 C/D

#define MFMA16(a, b, c) __builtin_amdgcn_mfma_f32_16x16x32_bf16((a), (b), (c), 0, 0, 0)

#define GLL16(g, l)                                                            \
  __builtin_amdgcn_global_load_lds(                                            \
      (const __attribute__((address_space(1))) void*)(g),                      \
      (__attribute__((address_space(3))) void*)(l), 16, 0, 0)

__device__ __forceinline__ u16 f2bf(float f) {  // RNE fp32 -> bf16 bits
  union { float f; unsigned u; } v; v.f = f;
  unsigned u = v.u;
  return (u16)((u + 0x7FFFu + ((u >> 16) & 1u)) >> 16);
}

// ---------------------------------------------------------------------------
// 0) weights fp32 -> bf16 (wq|wk|wv|wp contiguous: 4 x 65536)
__global__ __launch_bounds__(256) void conv_w(const float* __restrict__ s0,
                                              const float* __restrict__ s1,
                                              const float* __restrict__ s2,
                                              const float* __restrict__ s3,
                                              u16* __restrict__ dst) {
  const int m = blockIdx.y;
  const float* s = (m == 0) ? s0 : (m == 1) ? s1 : (m == 2) ? s2 : s3;
  const int i = (blockIdx.x * 256 + threadIdx.x) * 4;
  float4 v = *(const float4*)(s + i);
  u16* d = dst + m * 65536 + i;
  d[0] = f2bf(v.x); d[1] = f2bf(v.y); d[2] = f2bf(v.z); d[3] = f2bf(v.w);
}

// ---------------------------------------------------------------------------
// 1) GroupNorm stats: one block per (b,g) contiguous 32768-float chunk.
__global__ __launch_bounds__(256) void gn_stats(const float* __restrict__ x,
                                                float2* __restrict__ stats) {
  const int bg = blockIdx.x;
  const float* p = x + (long)bg * 32768;
  const int tid = threadIdx.x;
  float s = 0.f, ss = 0.f;
  #pragma unroll 8
  for (int i = 0; i < 32; ++i) {
    float4 v = *(const float4*)(p + tid * 4 + i * 1024);
    s  += v.x + v.y + v.z + v.w;
    ss += v.x * v.x + v.y * v.y + v.z * v.z + v.w * v.w;
  }
  for (int off = 32; off; off >>= 1) {
    s  += __shfl_down(s, off);
    ss += __shfl_down(ss, off);
  }
  __shared__ float2 red[4];
  if ((tid & 63) == 0) red[tid >> 6] = make_float2(s, ss);
  __syncthreads();
  if (tid == 0) {
    float S  = red[0].x + red[1].x + red[2].x + red[3].x;
    float SS = red[0].y + red[1].y + red[2].y + red[3].y;
    float mean = S * (1.f / 32768.f);
    float var  = SS * (1.f / 32768.f) - mean * mean;
    stats[bg] = make_float2(mean, rsqrtf(var + 1e-5f));
  }
}

// ---------------------------------------------------------------------------
// 2) normalize + transpose: x (B,C,T) f32 -> h_t (B,T,C) bf16.
__global__ __launch_bounds__(256) void gn_apply(const float* __restrict__ x,
                                                const float2* __restrict__ stats,
                                                const float* __restrict__ gamma,
                                                const float* __restrict__ beta,
                                                u16* __restrict__ h_t) {
  __shared__ float tile[64][65];
  const int tid = threadIdx.x;
  const int b = blockIdx.z, c0 = blockIdx.y * 64, t0 = blockIdx.x * 64;
  {
    const int ci = tid >> 2, tj0 = (tid & 3) * 16;
    const int c = c0 + ci;
    float2 st = stats[b * 32 + (c >> 3)];
    float gm = gamma[c] * st.y;
    float bt = beta[c] - st.x * gm;
    const float* xp = x + ((long)(b * 256 + c) * 4096 + t0 + tj0);
    #pragma unroll
    for (int i = 0; i < 4; ++i) {
      float4 v = *(const float4*)(xp + i * 4);
      tile[ci][tj0 + i * 4 + 0] = v.x * gm + bt;
      tile[ci][tj0 + i * 4 + 1] = v.y * gm + bt;
      tile[ci][tj0 + i * 4 + 2] = v.z * gm + bt;
      tile[ci][tj0 + i * 4 + 3] = v.w * gm + bt;
    }
  }
  __syncthreads();
  {
    const int tj = tid >> 2, ci0 = (tid & 3) * 16;
    u16* hp = h_t + ((long)(b * 4096 + t0 + tj) * 256 + c0 + ci0);
    short8 v0, v1;
    #pragma unroll
    for (int i = 0; i < 8; ++i) v0[i] = (short)f2bf(tile[ci0 + i][tj]);
    #pragma unroll
    for (int i = 0; i < 8; ++i) v1[i] = (short)f2bf(tile[ci0 + 8 + i][tj]);
    *(short8*)hp = v0;
    *(short8*)(hp + 8) = v1;
  }
}

// ---------------------------------------------------------------------------
// gemm_bt (128x128 tile, BK=32, 4 waves, XOR granule swizzle).
template <bool ROW_BIAS, bool RESID>
__global__ __launch_bounds__(256, 2) void gemm_bt(
    const u16* __restrict__ A, long strideAz, const u16* __restrict__ B,
    long strideBz, const float* __restrict__ bias, float scale,
    u16* __restrict__ outb, float* __restrict__ outf,
    const float* __restrict__ resid, long strideOz, int N) {
  __shared__ u16 a_lds[128 * 32];
  __shared__ u16 b_lds[128 * 32];
  const int tid = threadIdx.x, w = tid >> 6, l = tid & 63;
  const int l15 = l & 15, l4 = l >> 4;
  const int bz = blockIdx.z;
  A += bz * strideAz;
  B += bz * strideBz;
  const long obase = (long)bz * strideOz;
  const int m0 = blockIdx.y * 128, n0 = blockIdx.x * 128;
  const int wm = (w >> 1) * 64, wn = (w & 1) * 64;

  f32x4 acc[4][4];
  #pragma unroll
  for (int i = 0; i < 4; ++i)
    #pragma unroll
    for (int j = 0; j < 4; ++j) acc[i][j] = (f32x4)0.f;

  for (int kt = 0; kt < 8; ++kt) {
    const int k0 = kt * 32;
    __syncthreads();
    #pragma unroll
    for (int j = 0; j < 2; ++j) {
      const int r0 = (w * 2 + j) * 16;
      const int row = r0 + (l >> 2);
      const int sg = (l & 3) ^ (row & 3);
      GLL16(A + (long)(m0 + row) * 256 + k0 + sg * 8, a_lds + r0 * 32);
      GLL16(B + (long)(n0 + row) * 256 + k0 + sg * 8, b_lds + r0 * 32);
    }
    __syncthreads();
    short8 af[4], bf[4];
    #pragma unroll
    for (int t = 0; t < 4; ++t) {
      const int ra = wm + t * 16 + l15;
      af[t] = *(const short8*)(a_lds + ra * 32 + ((l4 ^ (ra & 3)) * 8));
      const int rb = wn + t * 16 + l15;
      bf[t] = *(const short8*)(b_lds + rb * 32 + ((l4 ^ (rb & 3)) * 8));
    }
    #pragma unroll
    for (int mt = 0; mt < 4; ++mt)
      #pragma unroll
      for (int nt = 0; nt < 4; ++nt) acc[mt][nt] = MFMA16(af[mt], bf[nt], acc[mt][nt]);
  }

  if (!ROW_BIAS) {
    float bv[4];
    #pragma unroll
    for (int nt = 0; nt < 4; ++nt) bv[nt] = bias[n0 + wn + nt * 16 + l15];
    #pragma unroll
    for (int mt = 0; mt < 4; ++mt)
      #pragma unroll
      for (int nt = 0; nt < 4; ++nt)
        #pragma unroll
        for (int r = 0; r < 4; ++r) {
          const int row = m0 + wm + mt * 16 + l4 * 4 + r;
          const int col = n0 + wn + nt * 16 + l15;
          outb[obase + (long)row * N + col] = f2bf((acc[mt][nt][r] + bv[nt]) * scale);
        }
  } else {
    float bm[4][4];
    #pragma unroll
    for (int mt = 0; mt < 4; ++mt)
      #pragma unroll
      for (int r = 0; r < 4; ++r) bm[mt][r] = bias[m0 + wm + mt * 16 + l4 * 4 + r];
    #pragma unroll
    for (int mt = 0; mt < 4; ++mt)
      #pragma unroll
      for (int nt = 0; nt < 4; ++nt)
        #pragma unroll
        for (int r = 0; r < 4; ++r) {
          const int row = m0 + wm + mt * 16 + l4 * 4 + r;
          const int col = n0 + wn + nt * 16 + l15;
          const long idx = obase + (long)row * N + col;
          float v = acc[mt][nt][r] + bm[mt][r];
          if (RESID) outf[idx] = v + resid[idx];
          else       outb[idx] = f2bf(v);
        }
  }
}

// ---------------------------------------------------------------------------
// merged Q+K projection: A (32768x256) x Bw(512x256)^T; cols 0-255 -> Qs
// (scaled 1/16, bias bq), cols 256-511 -> Ks (bias bk). One pass over h_t.
__global__ __launch_bounds__(256, 2) void gemm_qk(
    const u16* __restrict__ A, const u16* __restrict__ Bw,
    const float* __restrict__ bq, const float* __restrict__ bk,
    u16* __restrict__ Qs, u16* __restrict__ Ks) {
  __shared__ u16 a_lds[128 * 32];
  __shared__ u16 b_lds[128 * 32];
  const int tid = threadIdx.x, w = tid >> 6, l = tid & 63;
  const int l15 = l & 15, l4 = l >> 4;
  const int m0 = blockIdx.y * 128, n0 = blockIdx.x * 128;
  const int wm = (w >> 1) * 64, wn = (w & 1) * 64;

  f32x4 acc[4][4];
  #pragma unroll
  for (int i = 0; i < 4; ++i)
    #pragma unroll
    for (int j = 0; j < 4; ++j) acc[i][j] = (f32x4)0.f;

  for (int kt = 0; kt < 8; ++kt) {
    const int k0 = kt * 32;
    __syncthreads();
    #pragma unroll
    for (int j = 0; j < 2; ++j) {
      const int r0 = (w * 2 + j) * 16;
      const int row = r0 + (l >> 2);
      const int sg = (l & 3) ^ (row & 3);
      GLL16(A + (long)(m0 + row) * 256 + k0 + sg * 8, a_lds + r0 * 32);
      GLL16(Bw + (long)(n0 + row) * 256 + k0 + sg * 8, b_lds + r0 * 32);
    }
    __syncthreads();
    short8 af[4], bf[4];
    #pragma unroll
    for (int t = 0; t < 4; ++t) {
      const int ra = wm + t * 16 + l15;
      af[t] = *(const short8*)(a_lds + ra * 32 + ((l4 ^ (ra & 3)) * 8));
      const int rb = wn + t * 16 + l15;
      bf[t] = *(const short8*)(b_lds + rb * 32 + ((l4 ^ (rb & 3)) * 8));
    }
    #pragma unroll
    for (int mt = 0; mt < 4; ++mt)
      #pragma unroll
      for (int nt = 0; nt < 4; ++nt) acc[mt][nt] = MFMA16(af[mt], bf[nt], acc[mt][nt]);
  }

  const bool isQ = n0 < 256;
  u16* out = isQ ? Qs : Ks;
  const float* bias = isQ ? bq : bk;
  const float scale = isQ ? 0.0625f : 1.0f;
  const int nc0 = n0 & 255;
  float bv[4];
  #pragma unroll
  for (int nt = 0; nt < 4; ++nt) bv[nt] = bias[nc0 + wn + nt * 16 + l15];
  #pragma unroll
  for (int mt = 0; mt < 4; ++mt)
    #pragma unroll
    for (int nt = 0; nt < 4; ++nt)
      #pragma unroll
      for (int r = 0; r < 4; ++r) {
        const int row = m0 + wm + mt * 16 + l4 * 4 + r;
        const int col = nc0 + wn + nt * 16 + l15;
        out[(long)row * 256 + col] = f2bf((acc[mt][nt][r] + bv[nt]) * scale);
      }
}

// ---------------------------------------------------------------------------
// attention (R1 structure + register-pipelined staging):
// block = (batch, 64 q rows), 64 s-tiles of 64. Wave quadrants: S rows
// 32*(w>>1) x cols 32*(w&1); O rows 32*(w>>1) x cols 128*(w&1).
// Per tile: B1 -> ds_write staged K/V (waits on loads issued last iter) ->
// B2 -> [prefetch K(st+1)] -> S MFMA + exp + P write -> B3 -> [prefetch
// V(st+1)] -> PV MFMA. No-max softmax; divide by rowsum at the end.
__global__ __launch_bounds__(256, 2) void attn_kernel(
    const u16* __restrict__ Qs, const u16* __restrict__ Ks,
    const u16* __restrict__ Vt, u16* __restrict__ Z) {
  __shared__ u16 k_lds[16384];  // 64 x 256 (granule-swizzled), 32 KiB
  __shared__ u16 v_lds[16384];  // 256 x 64 (granule-swizzled), 32 KiB
  __shared__ u16 p_lds[64 * 72];  // 9 KiB, separate -> no post-S barrier
  __shared__ float l_buf[128];

  const int tid = threadIdx.x, w = tid >> 6, l = tid & 63;
  const int l15 = l & 15, l4 = l >> 4;
  const int bid = blockIdx.x;
  const int batch = bid & 7;   // bid%8: one batch per XCD if XCD = bid%8
  const int qt = bid >> 3;
  const int wrow0 = (w >> 1) * 32, wcolS = (w & 1) * 32, wcolO = (w & 1) * 128;
  const long qrow_base = (long)batch * 4096 + qt * 64;

  const u16* kbase = Ks + (long)batch * 4096 * 256;
  const u16* vbase = Vt + (long)batch * 256 * 4096;

  // Q fragments in registers: rows wrow0..wrow0+31, all 256 k. 64 VGPR.
  short8 qf[2][8];
  {
    const u16* qp = Qs + (qrow_base + wrow0) * 256;
    #pragma unroll
    for (int mt = 0; mt < 2; ++mt)
      #pragma unroll
      for (int ks = 0; ks < 8; ++ks)
        qf[mt][ks] = *(const short8*)(qp + (mt * 16 + l15) * 256 + ks * 32 + l4 * 8);
  }

  // staging addresses (match R1's GLL layout exactly; swizzle j-invariant)
  const int rowk = 2 * w + (l >> 5);
  const int sgk = (l & 31) ^ (rowk & 7);
  const u16* kg = kbase + (long)rowk * 256 + sgk * 8;  // += 16384/tile, j*2048
  const int cv = 8 * w + (l >> 3);
  const int sgv = (l & 7) ^ (cv & 7);
  const u16* vg = vbase + (long)cv * 4096 + sgv * 8;   // += 64/tile, j*131072
  u16* kw = k_lds + w * 512 + l * 8;                   // lane-linear, + j*2048
  u16* vw = v_lds + w * 512 + l * 8;

  float4 kpf[8], vpf[8];
  #pragma unroll
  for (int j = 0; j < 8; ++j) kpf[j] = *(const float4*)(kg + j * 2048);
  kg += 16384;
  #pragma unroll
  for (int j = 0; j < 8; ++j) vpf[j] = *(const float4*)(vg + (long)j * 131072);
  vg += 64;

  f32x4 o_acc[2][8];
  #pragma unroll
  for (int mt = 0; mt < 2; ++mt)
    #pragma unroll
    for (int nt = 0; nt < 8; ++nt) o_acc[mt][nt] = (f32x4)0.f;
  float rs[2][4] = {{0.f, 0.f, 0.f, 0.f}, {0.f, 0.f, 0.f, 0.f}};

  for (int st = 0; st < 64; ++st) {
    __syncthreads();  // B1: PV(st-1) done reading k/v/p
    #pragma unroll
    for (int j = 0; j < 8; ++j) *(float4*)(kw + j * 2048) = kpf[j];
    #pragma unroll
    for (int j = 0; j < 8; ++j) *(float4*)(vw + j * 2048) = vpf[j];
    __syncthreads();  // B2: staging visible

    if (st < 63) {  // prefetch K(st+1); waited at next B1/ds_write
      #pragma unroll
      for (int j = 0; j < 8; ++j) kpf[j] = *(const float4*)(kg + j * 2048);
      kg += 16384;
    }

    // S = Q K^T (quadrant 32x32), Q prescaled by 1/16
    f32x4 sacc[2][2];
    #pragma unroll
    for (int i = 0; i < 2; ++i)
      #pragma unroll
      for (int j = 0; j < 2; ++j) sacc[i][j] = (f32x4)0.f;
    #pragma unroll
    for (int ks = 0; ks < 8; ++ks) {
      short8 kf[2];
      #pragma unroll
      for (int nt = 0; nt < 2; ++nt) {
        const int row = wcolS + nt * 16 + l15;
        const int gk = (ks * 4 + l4) ^ (row & 7);
        kf[nt] = *(const short8*)(k_lds + row * 256 + gk * 8);
      }
      #pragma unroll
      for (int mt = 0; mt < 2; ++mt)
        #pragma unroll
        for (int nt = 0; nt < 2; ++nt) sacc[mt][nt] = MFMA16(qf[mt][ks], kf[nt], sacc[mt][nt]);
    }

    // P = exp(S); rowsums; P -> p_lds (separate buffer, no barrier needed)
    #pragma unroll
    for (int mt = 0; mt < 2; ++mt)
      #pragma unroll
      for (int nt = 0; nt < 2; ++nt)
        #pragma unroll
        for (int r = 0; r < 4; ++r) {
          float p = __expf(sacc[mt][nt][r]);
          rs[mt][r] += p;
          const int prow = wrow0 + mt * 16 + l4 * 4 + r;
          const int pcol = wcolS + nt * 16 + l15;
          p_lds[prow * 72 + pcol] = f2bf(p);
        }
    __syncthreads();  // B3: P visible

    if (st < 63) {  // prefetch V(st+1); waited at next B1/ds_write
      #pragma unroll
      for (int j = 0; j < 8; ++j) vpf[j] = *(const float4*)(vg + (long)j * 131072);
      vg += 64;
    }

    // O += P V
    #pragma unroll
    for (int ks2 = 0; ks2 < 2; ++ks2) {
      short8 pa[2];
      #pragma unroll
      for (int mt = 0; mt < 2; ++mt)
        pa[mt] = *(const short8*)(p_lds + (wrow0 + mt * 16 + l15) * 72 + ks2 * 32 + l4 * 8);
      #pragma unroll
      for (int nt = 0; nt < 8; ++nt) {
        const int c = wcolO + nt * 16 + l15;
        const int gv = (ks2 * 4 + l4) ^ (c & 7);
        short8 vb = *(const short8*)(v_lds + c * 64 + gv * 8);
        #pragma unroll
        for (int mt = 0; mt < 2; ++mt) o_acc[mt][nt] = MFMA16(pa[mt], vb, o_acc[mt][nt]);
      }
    }
  }

  // rowsum: reduce across the 16 lanes of each quad-group
  #pragma unroll
  for (int mt = 0; mt < 2; ++mt)
    #pragma unroll
    for (int r = 0; r < 4; ++r) {
      float v = rs[mt][r];
      v += __shfl_xor(v, 1); v += __shfl_xor(v, 2);
      v += __shfl_xor(v, 4); v += __shfl_xor(v, 8);
      rs[mt][r] = v;
    }
  if (l15 == 0) {
    #pragma unroll
    for (int mt = 0; mt < 2; ++mt)
      #pragma unroll
      for (int r = 0; r < 4; ++r)
        l_buf[(w & 1) * 64 + wrow0 + mt * 16 + l4 * 4 + r] = rs[mt][r];
  }
  __syncthreads();

  // normalize + store Z (B,T,C) bf16 (R1 epilogue: WRITE_SIZE was clean 16 MB)
  #pragma unroll
  for (int mt = 0; mt < 2; ++mt) {
    float inv[4];
    #pragma unroll
    for (int r = 0; r < 4; ++r) {
      const int row = wrow0 + mt * 16 + l4 * 4 + r;
      inv[r] = 1.f / (l_buf[row] + l_buf[64 + row]);
    }
    #pragma unroll
    for (int nt = 0; nt < 8; ++nt) {
      const int col = wcolO + nt * 16 + l15;
      #pragma unroll
      for (int r = 0; r < 4; ++r) {
        const long row = qrow_base + wrow0 + mt * 16 + l4 * 4 + r;
        Z[row * 256 + col] = f2bf(o_acc[mt][nt][r] * inv[r]);
      }
    }
  }
}

// ---------------------------------------------------------------------------
extern "C" void kernel_launch(void* const* d_in, const int* in_sizes, int n_in,
                              void* d_out, int out_size, void* d_ws, size_t ws_size,
                              hipStream_t stream) {
  (void)in_sizes; (void)n_in; (void)out_size; (void)ws_size;
  const float* x     = (const float*)d_in[0];
  const float* gamma = (const float*)d_in[1];
  const float* beta  = (const float*)d_in[2];
  const float* wq    = (const float*)d_in[3];
  const float* bq    = (const float*)d_in[4];
  const float* wk    = (const float*)d_in[5];
  const float* bk    = (const float*)d_in[6];
  const float* wv    = (const float*)d_in[7];
  const float* bv    = (const float*)d_in[8];
  const float* wp    = (const float*)d_in[9];
  const float* bp    = (const float*)d_in[10];
  float* out = (float*)d_out;

  char* ws = (char*)d_ws;
  u16*    wb    = (u16*)(ws);                  // 4 x 65536 bf16 (wq|wk|wv|wp)
  float2* stats = (float2*)(ws + 524288);      // 256 x float2
  u16*    h_t   = (u16*)(ws + 526336);         // (B,T,C) bf16
  u16*    Qs    = (u16*)(ws + 17303552);       // (B,T,C) bf16, prescaled /16
  u16*    Ks    = (u16*)(ws + 34080768);       // (B,T,C) bf16
  u16*    Vt    = (u16*)(ws + 50857984);       // (B,C,T) bf16
  u16*    Zb    = (u16*)(ws + 67635200);       // (B,T,C) bf16

  conv_w<<<dim3(64, 4), dim3(256), 0, stream>>>(wq, wk, wv, wp, wb);
  gn_stats<<<dim3(256), dim3(256), 0, stream>>>(x, stats);
  gn_apply<<<dim3(64, 4, 8), dim3(256), 0, stream>>>(x, stats, gamma, beta, h_t);

  const long sB = 4096L * 256L, sO = 256L * 4096L;
  // Q+K merged: (32768x256) x (512x256)^T, one pass over h_t
  gemm_qk<<<dim3(4, 256), dim3(256), 0, stream>>>(h_t, wb, bq, bk, Qs, Ks);
  // V^T per batch: (256x256) x (4096x256)^T -> (B,C,T)
  gemm_bt<true, false><<<dim3(32, 2, 8), dim3(256), 0, stream>>>(
      wb + 2 * 65536, 0L, h_t, sB, bv, 1.0f, Vt, nullptr, nullptr, sO, 4096);

  attn_kernel<<<dim3(512), dim3(256), 0, stream>>>(Qs, Ks, Vt, Zb);

  // proj per batch + bias + residual -> fp32 out (B,C,T)
  gemm_bt<true, true><<<dim3(32, 2, 8), dim3(256), 0, stream>>>(
      wb + 3 * 65536, 0L, Zb, sB, bp, 1.0f, nullptr, out, x, sO, 4096);
}

// Round 4
// 408.186 us; speedup vs baseline: 1.7650x; 1.7650x over previous
//
#include <hip/hip_runtime.h>

// ---------------------------------------------------------------------------
// SelfAttention (GN -> QKV 1x1 -> softmax(QK^T/16)V -> proj 1x1 + residual)
// B=8, C=256, GROUPS=32, H=W=64 -> T=4096. fp32 in/out, bf16 MFMA internally.
//
// R4 attention (all patterns from measured-good R1/R2 pieces):
//   - GLL staging of K/V tiles (R1 verbatim; R3's register prefetch spilled).
//   - S^T phase s-split 4 ways: wave w computes s in [w*16,+16) x all 64 q
//     (Q in 128 VGPR, R2-proven) -> K tile read ONCE from LDS.
//   - PV phase c-split 4 ways: wave w computes all 64 q x c in [w*64,+64)
//     with R1's 16-lane read patterns -> V read ONCE, P read 4x.
//   - LDS traffic 168 KB/block-tile vs R1's 216 KB (reads 96 KB vs 144 KB).
//   - separate p_lds -> 3 barriers/tile. No-max softmax (scores ~N(0,1)).
// ---------------------------------------------------------------------------

typedef unsigned short u16;
typedef __attribute__((ext_vector_type(8))) short short8;   // 8 bf16 = 4 VGPR
typedef __attribute__((ext_vector_type(4))) float f32x4;    // 16x16 C/D

#define MFMA16(a, b, c) __builtin_amdgcn_mfma_f32_16x16x32_bf16((a), (b), (c), 0, 0, 0)

#define GLL16(g, l)                                                            \
  __builtin_amdgcn_global_load_lds(                                            \
      (const __attribute__((address_space(1))) void*)(g),                      \
      (__attribute__((address_space(3))) void*)(l), 16, 0, 0)

__device__ __forceinline__ u16 f2bf(float f) {  // RNE fp32 -> bf16 bits
  union { float f; unsigned u; } v; v.f = f;
  unsigned u = v.u;
  return (u16)((u + 0x7FFFu + ((u >> 16) & 1u)) >> 16);
}

// ---------------------------------------------------------------------------
// 0) weights fp32 -> bf16 (wq|wk|wv|wp contiguous: 4 x 65536)
__global__ __launch_bounds__(256) void conv_w(const float* __restrict__ s0,
                                              const float* __restrict__ s1,
                                              const float* __restrict__ s2,
                                              const float* __restrict__ s3,
                                              u16* __restrict__ dst) {
  const int m = blockIdx.y;
  const float* s = (m == 0) ? s0 : (m == 1) ? s1 : (m == 2) ? s2 : s3;
  const int i = (blockIdx.x * 256 + threadIdx.x) * 4;
  float4 v = *(const float4*)(s + i);
  u16* d = dst + m * 65536 + i;
  d[0] = f2bf(v.x); d[1] = f2bf(v.y); d[2] = f2bf(v.z); d[3] = f2bf(v.w);
}

// ---------------------------------------------------------------------------
// 1) GroupNorm stats: one block per (b,g) contiguous 32768-float chunk.
__global__ __launch_bounds__(256) void gn_stats(const float* __restrict__ x,
                                                float2* __restrict__ stats) {
  const int bg = blockIdx.x;
  const float* p = x + (long)bg * 32768;
  const int tid = threadIdx.x;
  float s = 0.f, ss = 0.f;
  #pragma unroll 8
  for (int i = 0; i < 32; ++i) {
    float4 v = *(const float4*)(p + tid * 4 + i * 1024);
    s  += v.x + v.y + v.z + v.w;
    ss += v.x * v.x + v.y * v.y + v.z * v.z + v.w * v.w;
  }
  for (int off = 32; off; off >>= 1) {
    s  += __shfl_down(s, off);
    ss += __shfl_down(ss, off);
  }
  __shared__ float2 red[4];
  if ((tid & 63) == 0) red[tid >> 6] = make_float2(s, ss);
  __syncthreads();
  if (tid == 0) {
    float S  = red[0].x + red[1].x + red[2].x + red[3].x;
    float SS = red[0].y + red[1].y + red[2].y + red[3].y;
    float mean = S * (1.f / 32768.f);
    float var  = SS * (1.f / 32768.f) - mean * mean;
    stats[bg] = make_float2(mean, rsqrtf(var + 1e-5f));
  }
}

// ---------------------------------------------------------------------------
// 2) normalize + transpose: x (B,C,T) f32 -> h_t (B,T,C) bf16.
__global__ __launch_bounds__(256) void gn_apply(const float* __restrict__ x,
                                                const float2* __restrict__ stats,
                                                const float* __restrict__ gamma,
                                                const float* __restrict__ beta,
                                                u16* __restrict__ h_t) {
  __shared__ float tile[64][65];
  const int tid = threadIdx.x;
  const int b = blockIdx.z, c0 = blockIdx.y * 64, t0 = blockIdx.x * 64;
  {
    const int ci = tid >> 2, tj0 = (tid & 3) * 16;
    const int c = c0 + ci;
    float2 st = stats[b * 32 + (c >> 3)];
    float gm = gamma[c] * st.y;
    float bt = beta[c] - st.x * gm;
    const float* xp = x + ((long)(b * 256 + c) * 4096 + t0 + tj0);
    #pragma unroll
    for (int i = 0; i < 4; ++i) {
      float4 v = *(const float4*)(xp + i * 4);
      tile[ci][tj0 + i * 4 + 0] = v.x * gm + bt;
      tile[ci][tj0 + i * 4 + 1] = v.y * gm + bt;
      tile[ci][tj0 + i * 4 + 2] = v.z * gm + bt;
      tile[ci][tj0 + i * 4 + 3] = v.w * gm + bt;
    }
  }
  __syncthreads();
  {
    const int tj = tid >> 2, ci0 = (tid & 3) * 16;
    u16* hp = h_t + ((long)(b * 4096 + t0 + tj) * 256 + c0 + ci0);
    short8 v0, v1;
    #pragma unroll
    for (int i = 0; i < 8; ++i) v0[i] = (short)f2bf(tile[ci0 + i][tj]);
    #pragma unroll
    for (int i = 0; i < 8; ++i) v1[i] = (short)f2bf(tile[ci0 + 8 + i][tj]);
    *(short8*)hp = v0;
    *(short8*)(hp + 8) = v1;
  }
}

// ---------------------------------------------------------------------------
// gemm_bt (128x128 tile, BK=32, 4 waves, XOR granule swizzle).
template <bool ROW_BIAS, bool RESID>
__global__ __launch_bounds__(256, 2) void gemm_bt(
    const u16* __restrict__ A, long strideAz, const u16* __restrict__ B,
    long strideBz, const float* __restrict__ bias, float scale,
    u16* __restrict__ outb, float* __restrict__ outf,
    const float* __restrict__ resid, long strideOz, int N) {
  __shared__ u16 a_lds[128 * 32];
  __shared__ u16 b_lds[128 * 32];
  const int tid = threadIdx.x, w = tid >> 6, l = tid & 63;
  const int l15 = l & 15, l4 = l >> 4;
  const int bz = blockIdx.z;
  A += bz * strideAz;
  B += bz * strideBz;
  const long obase = (long)bz * strideOz;
  const int m0 = blockIdx.y * 128, n0 = blockIdx.x * 128;
  const int wm = (w >> 1) * 64, wn = (w & 1) * 64;

  f32x4 acc[4][4];
  #pragma unroll
  for (int i = 0; i < 4; ++i)
    #pragma unroll
    for (int j = 0; j < 4; ++j) acc[i][j] = (f32x4)0.f;

  for (int kt = 0; kt < 8; ++kt) {
    const int k0 = kt * 32;
    __syncthreads();
    #pragma unroll
    for (int j = 0; j < 2; ++j) {
      const int r0 = (w * 2 + j) * 16;
      const int row = r0 + (l >> 2);
      const int sg = (l & 3) ^ (row & 3);
      GLL16(A + (long)(m0 + row) * 256 + k0 + sg * 8, a_lds + r0 * 32);
      GLL16(B + (long)(n0 + row) * 256 + k0 + sg * 8, b_lds + r0 * 32);
    }
    __syncthreads();
    short8 af[4], bf[4];
    #pragma unroll
    for (int t = 0; t < 4; ++t) {
      const int ra = wm + t * 16 + l15;
      af[t] = *(const short8*)(a_lds + ra * 32 + ((l4 ^ (ra & 3)) * 8));
      const int rb = wn + t * 16 + l15;
      bf[t] = *(const short8*)(b_lds + rb * 32 + ((l4 ^ (rb & 3)) * 8));
    }
    #pragma unroll
    for (int mt = 0; mt < 4; ++mt)
      #pragma unroll
      for (int nt = 0; nt < 4; ++nt) acc[mt][nt] = MFMA16(af[mt], bf[nt], acc[mt][nt]);
  }

  if (!ROW_BIAS) {
    float bv[4];
    #pragma unroll
    for (int nt = 0; nt < 4; ++nt) bv[nt] = bias[n0 + wn + nt * 16 + l15];
    #pragma unroll
    for (int mt = 0; mt < 4; ++mt)
      #pragma unroll
      for (int nt = 0; nt < 4; ++nt)
        #pragma unroll
        for (int r = 0; r < 4; ++r) {
          const int row = m0 + wm + mt * 16 + l4 * 4 + r;
          const int col = n0 + wn + nt * 16 + l15;
          outb[obase + (long)row * N + col] = f2bf((acc[mt][nt][r] + bv[nt]) * scale);
        }
  } else {
    float bm[4][4];
    #pragma unroll
    for (int mt = 0; mt < 4; ++mt)
      #pragma unroll
      for (int r = 0; r < 4; ++r) bm[mt][r] = bias[m0 + wm + mt * 16 + l4 * 4 + r];
    #pragma unroll
    for (int mt = 0; mt < 4; ++mt)
      #pragma unroll
      for (int nt = 0; nt < 4; ++nt)
        #pragma unroll
        for (int r = 0; r < 4; ++r) {
          const int row = m0 + wm + mt * 16 + l4 * 4 + r;
          const int col = n0 + wn + nt * 16 + l15;
          const long idx = obase + (long)row * N + col;
          float v = acc[mt][nt][r] + bm[mt][r];
          if (RESID) outf[idx] = v + resid[idx];
          else       outb[idx] = f2bf(v);
        }
  }
}

// ---------------------------------------------------------------------------
// merged Q+K projection: A (32768x256) x Bw(512x256)^T; cols 0-255 -> Qs
// (scaled 1/16, bias bq), cols 256-511 -> Ks (bias bk). One pass over h_t.
__global__ __launch_bounds__(256, 2) void gemm_qk(
    const u16* __restrict__ A, const u16* __restrict__ Bw,
    const float* __restrict__ bq, const float* __restrict__ bk,
    u16* __restrict__ Qs, u16* __restrict__ Ks) {
  __shared__ u16 a_lds[128 * 32];
  __shared__ u16 b_lds[128 * 32];
  const int tid = threadIdx.x, w = tid >> 6, l = tid & 63;
  const int l15 = l & 15, l4 = l >> 4;
  const int m0 = blockIdx.y * 128, n0 = blockIdx.x * 128;
  const int wm = (w >> 1) * 64, wn = (w & 1) * 64;

  f32x4 acc[4][4];
  #pragma unroll
  for (int i = 0; i < 4; ++i)
    #pragma unroll
    for (int j = 0; j < 4; ++j) acc[i][j] = (f32x4)0.f;

  for (int kt = 0; kt < 8; ++kt) {
    const int k0 = kt * 32;
    __syncthreads();
    #pragma unroll
    for (int j = 0; j < 2; ++j) {
      const int r0 = (w * 2 + j) * 16;
      const int row = r0 + (l >> 2);
      const int sg = (l & 3) ^ (row & 3);
      GLL16(A + (long)(m0 + row) * 256 + k0 + sg * 8, a_lds + r0 * 32);
      GLL16(Bw + (long)(n0 + row) * 256 + k0 + sg * 8, b_lds + r0 * 32);
    }
    __syncthreads();
    short8 af[4], bf[4];
    #pragma unroll
    for (int t = 0; t < 4; ++t) {
      const int ra = wm + t * 16 + l15;
      af[t] = *(const short8*)(a_lds + ra * 32 + ((l4 ^ (ra & 3)) * 8));
      const int rb = wn + t * 16 + l15;
      bf[t] = *(const short8*)(b_lds + rb * 32 + ((l4 ^ (rb & 3)) * 8));
    }
    #pragma unroll
    for (int mt = 0; mt < 4; ++mt)
      #pragma unroll
      for (int nt = 0; nt < 4; ++nt) acc[mt][nt] = MFMA16(af[mt], bf[nt], acc[mt][nt]);
  }

  const bool isQ = n0 < 256;
  u16* out = isQ ? Qs : Ks;
  const float* bias = isQ ? bq : bk;
  const float scale = isQ ? 0.0625f : 1.0f;
  const int nc0 = n0 & 255;
  float bv[4];
  #pragma unroll
  for (int nt = 0; nt < 4; ++nt) bv[nt] = bias[nc0 + wn + nt * 16 + l15];
  #pragma unroll
  for (int mt = 0; mt < 4; ++mt)
    #pragma unroll
    for (int nt = 0; nt < 4; ++nt)
      #pragma unroll
      for (int r = 0; r < 4; ++r) {
        const int row = m0 + wm + mt * 16 + l4 * 4 + r;
        const int col = nc0 + wn + nt * 16 + l15;
        out[(long)row * 256 + col] = f2bf((acc[mt][nt][r] + bv[nt]) * scale);
      }
}

// ---------------------------------------------------------------------------
// attention R4: block = (batch, 64 q rows); 64 s-tiles of 64 streamed.
// S^T phase (s-split): wave w -> s in [w*16,+16) x all 64 q; K read once.
//   D[m=s][n=q] = MFMA16(A=K-frag, B=Q-frag); C-layout: s=w*16+l4*4+r, q=mt*16+l15.
// PV phase (c-split): wave w -> all 64 q x c in [w*64,+64); V read once, P 4x.
//   D[m=q][n=c] = MFMA16(A=P[q][s], B=V-frag).
// GLL staging (R1), separate p_lds[q][72], 3 barriers/tile.
__global__ __launch_bounds__(256, 2) void attn_kernel(
    const u16* __restrict__ Qs, const u16* __restrict__ Ks,
    const u16* __restrict__ Vt, u16* __restrict__ Z) {
  __shared__ u16 k_lds[16384];    // 64 x 256 (granule-swizzled), 32 KiB
  __shared__ u16 v_lds[16384];    // 256 x 64 (granule-swizzled), 32 KiB
  __shared__ u16 p_lds[64 * 72];  // [q][s], pad 8 -> 9 KiB
  __shared__ float l_red[256];    // [wave][q] rowsum partials -> inv totals

  const int tid = threadIdx.x, w = tid >> 6, l = tid & 63;
  const int l15 = l & 15, l4 = l >> 4;
  const int bid = blockIdx.x;
  const int batch = bid & 7;   // bid%8: one batch per XCD if XCD = bid%8
  const int qt = bid >> 3;
  const long qrow_base = (long)batch * 4096 + qt * 64;

  const u16* kbase = Ks + (long)batch * 4096 * 256;
  const u16* vbase = Vt + (long)batch * 256 * 4096;

  // Q fragments (B-operand of S^T): all 64 q rows x K=256. 128 VGPR.
  short8 qf[4][8];
  {
    const u16* qp = Qs + qrow_base * 256;
    #pragma unroll
    for (int mt = 0; mt < 4; ++mt)
      #pragma unroll
      for (int ks = 0; ks < 8; ++ks)
        qf[mt][ks] = *(const short8*)(qp + (mt * 16 + l15) * 256 + ks * 32 + l4 * 8);
  }

  f32x4 o_acc[4][4];  // [mt(q)][nt(c)]: q = mt*16+l4*4+r, c = w*64+nt*16+l15
  #pragma unroll
  for (int i = 0; i < 4; ++i)
    #pragma unroll
    for (int j = 0; j < 4; ++j) o_acc[i][j] = (f32x4)0.f;
  float rs[4] = {0.f, 0.f, 0.f, 0.f};  // rowsum partial for q=mt*16+l15 (this wave's s)

  for (int st = 0; st < 64; ++st) {
    const int sn0 = st * 64;
    __syncthreads();  // B1: PV(st-1) done reading k/v/p
    #pragma unroll
    for (int j = 0; j < 8; ++j) {  // K tile: 64 rows x 256
      const int r0 = (j * 4 + w) * 2;
      const int row = r0 + (l >> 5);
      const int sg = (l & 31) ^ (row & 7);
      GLL16(kbase + (long)(sn0 + row) * 256 + sg * 8, k_lds + r0 * 256);
    }
    #pragma unroll
    for (int j = 0; j < 8; ++j) {  // V tile: 256 rows x 64
      const int c0 = (j * 4 + w) * 8;
      const int c = c0 + (l >> 3);
      const int sg = (l & 7) ^ (c & 7);
      GLL16(vbase + (long)c * 4096 + sn0 + sg * 8, v_lds + c0 * 64);
    }
    __syncthreads();  // B2: staging visible

    // S^T for s rows [w*16,+16): A = K[s][k] (row = w*16+l15), B = qf[mt]
    f32x4 sacc[4];
    #pragma unroll
    for (int mt = 0; mt < 4; ++mt) sacc[mt] = (f32x4)0.f;
    const u16* kro = k_lds + (w * 16 + l15) * 256;
    #pragma unroll
    for (int ks = 0; ks < 8; ++ks) {
      short8 kf = *(const short8*)(kro + (((ks * 4 + l4) ^ (l15 & 7)) * 8));
      #pragma unroll
      for (int mt = 0; mt < 4; ++mt) sacc[mt] = MFMA16(kf, qf[mt][ks], sacc[mt]);
    }
    // exp + rowsum partial + P write: lane holds s=w*16+l4*4+r at q=mt*16+l15
    #pragma unroll
    for (int mt = 0; mt < 4; ++mt) {
      float e0 = __expf(sacc[mt][0]), e1 = __expf(sacc[mt][1]);
      float e2 = __expf(sacc[mt][2]), e3 = __expf(sacc[mt][3]);
      rs[mt] += (e0 + e1) + (e2 + e3);
      ushort4 pk = {f2bf(e0), f2bf(e1), f2bf(e2), f2bf(e3)};
      *(ushort4*)(p_lds + (mt * 16 + l15) * 72 + w * 16 + l4 * 4) = pk;
    }
    __syncthreads();  // B3: P visible (k_lds S-reads also done block-wide)

    // O += P V: A = P[q][s] (rows mt*16+l15), B = V[c][s] (rows w*64+nt*16+l15)
    #pragma unroll
    for (int ks2 = 0; ks2 < 2; ++ks2) {
      short8 pa[4], vb[4];
      #pragma unroll
      for (int mt = 0; mt < 4; ++mt)
        pa[mt] = *(const short8*)(p_lds + (mt * 16 + l15) * 72 + ks2 * 32 + l4 * 8);
      #pragma unroll
      for (int nt = 0; nt < 4; ++nt) {
        const int c = w * 64 + nt * 16 + l15;
        const int gv = (ks2 * 4 + l4) ^ (c & 7);
        vb[nt] = *(const short8*)(v_lds + c * 64 + gv * 8);
      }
      #pragma unroll
      for (int mt = 0; mt < 4; ++mt)
        #pragma unroll
        for (int nt = 0; nt < 4; ++nt)
          o_acc[mt][nt] = MFMA16(pa[mt], vb[nt], o_acc[mt][nt]);
    }
  }

  // rowsums: reduce over l4 (the wave's 4 s-strips), then across waves
  #pragma unroll
  for (int mt = 0; mt < 4; ++mt) {
    float v = rs[mt];
    v += __shfl_xor(v, 16);
    v += __shfl_xor(v, 32);
    if (l4 == 0) l_red[w * 64 + mt * 16 + l15] = v;
  }
  __syncthreads();
  if (tid < 64) {
    float t = l_red[tid] + l_red[64 + tid] + l_red[128 + tid] + l_red[192 + tid];
    l_red[tid] = 1.f / t;
  }
  __syncthreads();

  // store Z (B,T,C) bf16: q = mt*16+l4*4+r, c = w*64+nt*16+l15
  #pragma unroll
  for (int mt = 0; mt < 4; ++mt) {
    float inv[4];
    #pragma unroll
    for (int r = 0; r < 4; ++r) inv[r] = l_red[mt * 16 + l4 * 4 + r];
    #pragma unroll
    for (int nt = 0; nt < 4; ++nt) {
      const int col = w * 64 + nt * 16 + l15;
      #pragma unroll
      for (int r = 0; r < 4; ++r) {
        const long row = qrow_base + mt * 16 + l4 * 4 + r;
        Z[row * 256 + col] = f2bf(o_acc[mt][nt][r] * inv[r]);
      }
    }
  }
}

// ---------------------------------------------------------------------------
extern "C" void kernel_launch(void* const* d_in, const int* in_sizes, int n_in,
                              void* d_out, int out_size, void* d_ws, size_t ws_size,
                              hipStream_t stream) {
  (void)in_sizes; (void)n_in; (void)out_size; (void)ws_size;
  const float* x     = (const float*)d_in[0];
  const float* gamma = (const float*)d_in[1];
  const float* beta  = (const float*)d_in[2];
  const float* wq    = (const float*)d_in[3];
  const float* bq    = (const float*)d_in[4];
  const float* wk    = (const float*)d_in[5];
  const float* bk    = (const float*)d_in[6];
  const float* wv    = (const float*)d_in[7];
  const float* bv    = (const float*)d_in[8];
  const float* wp    = (const float*)d_in[9];
  const float* bp    = (const float*)d_in[10];
  float* out = (float*)d_out;

  char* ws = (char*)d_ws;
  u16*    wb    = (u16*)(ws);                  // 4 x 65536 bf16 (wq|wk|wv|wp)
  float2* stats = (float2*)(ws + 524288);      // 256 x float2
  u16*    h_t   = (u16*)(ws + 526336);         // (B,T,C) bf16
  u16*    Qs    = (u16*)(ws + 17303552);       // (B,T,C) bf16, prescaled /16
  u16*    Ks    = (u16*)(ws + 34080768);       // (B,T,C) bf16
  u16*    Vt    = (u16*)(ws + 50857984);       // (B,C,T) bf16
  u16*    Zb    = (u16*)(ws + 67635200);       // (B,T,C) bf16

  conv_w<<<dim3(64, 4), dim3(256), 0, stream>>>(wq, wk, wv, wp, wb);
  gn_stats<<<dim3(256), dim3(256), 0, stream>>>(x, stats);
  gn_apply<<<dim3(64, 4, 8), dim3(256), 0, stream>>>(x, stats, gamma, beta, h_t);

  const long sB = 4096L * 256L, sO = 256L * 4096L;
  // Q+K merged: (32768x256) x (512x256)^T, one pass over h_t
  gemm_qk<<<dim3(4, 256), dim3(256), 0, stream>>>(h_t, wb, bq, bk, Qs, Ks);
  // V^T per batch: (256x256) x (4096x256)^T -> (B,C,T)
  gemm_bt<true, false><<<dim3(32, 2, 8), dim3(256), 0, stream>>>(
      wb + 2 * 65536, 0L, h_t, sB, bv, 1.0f, Vt, nullptr, nullptr, sO, 4096);

  attn_kernel<<<dim3(512), dim3(256), 0, stream>>>(Qs, Ks, Vt, Zb);

  // proj per batch + bias + residual -> fp32 out (B,C,T)
  gemm_bt<true, true><<<dim3(32, 2, 8), dim3(256), 0, stream>>>(
      wb + 3 * 65536, 0L, Zb, sB, bp, 1.0f, nullptr, out, x, sO, 4096);
}

// Round 5
// 306.500 us; speedup vs baseline: 2.3506x; 1.3318x over previous
//
#include <hip/hip_runtime.h>

// ---------------------------------------------------------------------------
// SelfAttention (GN -> QKV 1x1 -> softmax(QK^T/16)V -> proj 1x1 + residual)
// B=8, C=256, GROUPS=32, H=W=64 -> T=4096. fp32 in/out, bf16 MFMA internally.
//
// R5 attention = R1 compute (191.7 us, 64-VGPR Q quadrants -- the only
// register-safe Q layout; R2/R3/R4's 128-VGPR Q all spilled to scratch) +
// software-pipelined GLL staging with raw s_barrier / s_waitcnt vmcnt(8):
//   - K(st+1) issued after post-P barrier (k_lds readers done), drains
//     during PV(st).  V(st+1) issued after post-PV barrier, drains during
//     S(st+1).  No barrier ever waits vmcnt(0): each waits on 8 loads
//     issued a full compute phase earlier.
//   - separate p_lds (9 KiB) removes R1's aliasing barrier.
//   - wrap-around issue at st=63 keeps 16 loads outstanding at every wait
//     point so vmcnt(8) always selects exactly the needed older 8.
// ---------------------------------------------------------------------------

typedef unsigned short u16;
typedef __attribute__((ext_vector_type(8))) short short8;   // 8 bf16 = 4 VGPR
typedef __attribute__((ext_vector_type(4))) float f32x4;    // 16x16 C/D

#define MFMA16(a, b, c) __builtin_amdgcn_mfma_f32_16x16x32_bf16((a), (b), (c), 0, 0, 0)

#define GLL16(g, l)                                                            \
  __builtin_amdgcn_global_load_lds(                                            \
      (const __attribute__((address_space(1))) void*)(g),                      \
      (__attribute__((address_space(3))) void*)(l), 16, 0, 0)

// pipeline barriers: wait only on loads issued a phase earlier, never vmcnt(0)
#define BAR_VM8()  asm volatile("s_waitcnt vmcnt(8)\n\ts_barrier" ::: "memory")
#define BAR_LGKM() asm volatile("s_waitcnt lgkmcnt(0)\n\ts_barrier" ::: "memory")

__device__ __forceinline__ u16 f2bf(float f) {  // RNE fp32 -> bf16 bits
  union { float f; unsigned u; } v; v.f = f;
  unsigned u = v.u;
  return (u16)((u + 0x7FFFu + ((u >> 16) & 1u)) >> 16);
}

// ---------------------------------------------------------------------------
// 0) weights fp32 -> bf16 (wq|wk|wv|wp contiguous: 4 x 65536)
__global__ __launch_bounds__(256) void conv_w(const float* __restrict__ s0,
                                              const float* __restrict__ s1,
                                              const float* __restrict__ s2,
                                              const float* __restrict__ s3,
                                              u16* __restrict__ dst) {
  const int m = blockIdx.y;
  const float* s = (m == 0) ? s0 : (m == 1) ? s1 : (m == 2) ? s2 : s3;
  const int i = (blockIdx.x * 256 + threadIdx.x) * 4;
  float4 v = *(const float4*)(s + i);
  u16* d = dst + m * 65536 + i;
  d[0] = f2bf(v.x); d[1] = f2bf(v.y); d[2] = f2bf(v.z); d[3] = f2bf(v.w);
}

// ---------------------------------------------------------------------------
// 1) GroupNorm stats: one block per (b,g) contiguous 32768-float chunk.
__global__ __launch_bounds__(256) void gn_stats(const float* __restrict__ x,
                                                float2* __restrict__ stats) {
  const int bg = blockIdx.x;
  const float* p = x + (long)bg * 32768;
  const int tid = threadIdx.x;
  float s = 0.f, ss = 0.f;
  #pragma unroll 8
  for (int i = 0; i < 32; ++i) {
    float4 v = *(const float4*)(p + tid * 4 + i * 1024);
    s  += v.x + v.y + v.z + v.w;
    ss += v.x * v.x + v.y * v.y + v.z * v.z + v.w * v.w;
  }
  for (int off = 32; off; off >>= 1) {
    s  += __shfl_down(s, off);
    ss += __shfl_down(ss, off);
  }
  __shared__ float2 red[4];
  if ((tid & 63) == 0) red[tid >> 6] = make_float2(s, ss);
  __syncthreads();
  if (tid == 0) {
    float S  = red[0].x + red[1].x + red[2].x + red[3].x;
    float SS = red[0].y + red[1].y + red[2].y + red[3].y;
    float mean = S * (1.f / 32768.f);
    float var  = SS * (1.f / 32768.f) - mean * mean;
    stats[bg] = make_float2(mean, rsqrtf(var + 1e-5f));
  }
}

// ---------------------------------------------------------------------------
// 2) normalize + transpose: x (B,C,T) f32 -> h_t (B,T,C) bf16.
__global__ __launch_bounds__(256) void gn_apply(const float* __restrict__ x,
                                                const float2* __restrict__ stats,
                                                const float* __restrict__ gamma,
                                                const float* __restrict__ beta,
                                                u16* __restrict__ h_t) {
  __shared__ float tile[64][65];
  const int tid = threadIdx.x;
  const int b = blockIdx.z, c0 = blockIdx.y * 64, t0 = blockIdx.x * 64;
  {
    const int ci = tid >> 2, tj0 = (tid & 3) * 16;
    const int c = c0 + ci;
    float2 st = stats[b * 32 + (c >> 3)];
    float gm = gamma[c] * st.y;
    float bt = beta[c] - st.x * gm;
    const float* xp = x + ((long)(b * 256 + c) * 4096 + t0 + tj0);
    #pragma unroll
    for (int i = 0; i < 4; ++i) {
      float4 v = *(const float4*)(xp + i * 4);
      tile[ci][tj0 + i * 4 + 0] = v.x * gm + bt;
      tile[ci][tj0 + i * 4 + 1] = v.y * gm + bt;
      tile[ci][tj0 + i * 4 + 2] = v.z * gm + bt;
      tile[ci][tj0 + i * 4 + 3] = v.w * gm + bt;
    }
  }
  __syncthreads();
  {
    const int tj = tid >> 2, ci0 = (tid & 3) * 16;
    u16* hp = h_t + ((long)(b * 4096 + t0 + tj) * 256 + c0 + ci0);
    short8 v0, v1;
    #pragma unroll
    for (int i = 0; i < 8; ++i) v0[i] = (short)f2bf(tile[ci0 + i][tj]);
    #pragma unroll
    for (int i = 0; i < 8; ++i) v1[i] = (short)f2bf(tile[ci0 + 8 + i][tj]);
    *(short8*)hp = v0;
    *(short8*)(hp + 8) = v1;
  }
}

// ---------------------------------------------------------------------------
// gemm_bt (128x128 tile, BK=32, 4 waves, XOR granule swizzle).
template <bool ROW_BIAS, bool RESID>
__global__ __launch_bounds__(256, 2) void gemm_bt(
    const u16* __restrict__ A, long strideAz, const u16* __restrict__ B,
    long strideBz, const float* __restrict__ bias, float scale,
    u16* __restrict__ outb, float* __restrict__ outf,
    const float* __restrict__ resid, long strideOz, int N) {
  __shared__ u16 a_lds[128 * 32];
  __shared__ u16 b_lds[128 * 32];
  const int tid = threadIdx.x, w = tid >> 6, l = tid & 63;
  const int l15 = l & 15, l4 = l >> 4;
  const int bz = blockIdx.z;
  A += bz * strideAz;
  B += bz * strideBz;
  const long obase = (long)bz * strideOz;
  const int m0 = blockIdx.y * 128, n0 = blockIdx.x * 128;
  const int wm = (w >> 1) * 64, wn = (w & 1) * 64;

  f32x4 acc[4][4];
  #pragma unroll
  for (int i = 0; i < 4; ++i)
    #pragma unroll
    for (int j = 0; j < 4; ++j) acc[i][j] = (f32x4)0.f;

  for (int kt = 0; kt < 8; ++kt) {
    const int k0 = kt * 32;
    __syncthreads();
    #pragma unroll
    for (int j = 0; j < 2; ++j) {
      const int r0 = (w * 2 + j) * 16;
      const int row = r0 + (l >> 2);
      const int sg = (l & 3) ^ (row & 3);
      GLL16(A + (long)(m0 + row) * 256 + k0 + sg * 8, a_lds + r0 * 32);
      GLL16(B + (long)(n0 + row) * 256 + k0 + sg * 8, b_lds + r0 * 32);
    }
    __syncthreads();
    short8 af[4], bf[4];
    #pragma unroll
    for (int t = 0; t < 4; ++t) {
      const int ra = wm + t * 16 + l15;
      af[t] = *(const short8*)(a_lds + ra * 32 + ((l4 ^ (ra & 3)) * 8));
      const int rb = wn + t * 16 + l15;
      bf[t] = *(const short8*)(b_lds + rb * 32 + ((l4 ^ (rb & 3)) * 8));
    }
    #pragma unroll
    for (int mt = 0; mt < 4; ++mt)
      #pragma unroll
      for (int nt = 0; nt < 4; ++nt) acc[mt][nt] = MFMA16(af[mt], bf[nt], acc[mt][nt]);
  }

  if (!ROW_BIAS) {
    float bv[4];
    #pragma unroll
    for (int nt = 0; nt < 4; ++nt) bv[nt] = bias[n0 + wn + nt * 16 + l15];
    #pragma unroll
    for (int mt = 0; mt < 4; ++mt)
      #pragma unroll
      for (int nt = 0; nt < 4; ++nt)
        #pragma unroll
        for (int r = 0; r < 4; ++r) {
          const int row = m0 + wm + mt * 16 + l4 * 4 + r;
          const int col = n0 + wn + nt * 16 + l15;
          outb[obase + (long)row * N + col] = f2bf((acc[mt][nt][r] + bv[nt]) * scale);
        }
  } else {
    float bm[4][4];
    #pragma unroll
    for (int mt = 0; mt < 4; ++mt)
      #pragma unroll
      for (int r = 0; r < 4; ++r) bm[mt][r] = bias[m0 + wm + mt * 16 + l4 * 4 + r];
    #pragma unroll
    for (int mt = 0; mt < 4; ++mt)
      #pragma unroll
      for (int nt = 0; nt < 4; ++nt)
        #pragma unroll
        for (int r = 0; r < 4; ++r) {
          const int row = m0 + wm + mt * 16 + l4 * 4 + r;
          const int col = n0 + wn + nt * 16 + l15;
          const long idx = obase + (long)row * N + col;
          float v = acc[mt][nt][r] + bm[mt][r];
          if (RESID) outf[idx] = v + resid[idx];
          else       outb[idx] = f2bf(v);
        }
  }
}

// ---------------------------------------------------------------------------
// merged Q+K projection: A (32768x256) x Bw(512x256)^T; cols 0-255 -> Qs
// (scaled 1/16, bias bq), cols 256-511 -> Ks (bias bk). One pass over h_t.
__global__ __launch_bounds__(256, 2) void gemm_qk(
    const u16* __restrict__ A, const u16* __restrict__ Bw,
    const float* __restrict__ bq, const float* __restrict__ bk,
    u16* __restrict__ Qs, u16* __restrict__ Ks) {
  __shared__ u16 a_lds[128 * 32];
  __shared__ u16 b_lds[128 * 32];
  const int tid = threadIdx.x, w = tid >> 6, l = tid & 63;
  const int l15 = l & 15, l4 = l >> 4;
  const int m0 = blockIdx.y * 128, n0 = blockIdx.x * 128;
  const int wm = (w >> 1) * 64, wn = (w & 1) * 64;

  f32x4 acc[4][4];
  #pragma unroll
  for (int i = 0; i < 4; ++i)
    #pragma unroll
    for (int j = 0; j < 4; ++j) acc[i][j] = (f32x4)0.f;

  for (int kt = 0; kt < 8; ++kt) {
    const int k0 = kt * 32;
    __syncthreads();
    #pragma unroll
    for (int j = 0; j < 2; ++j) {
      const int r0 = (w * 2 + j) * 16;
      const int row = r0 + (l >> 2);
      const int sg = (l & 3) ^ (row & 3);
      GLL16(A + (long)(m0 + row) * 256 + k0 + sg * 8, a_lds + r0 * 32);
      GLL16(Bw + (long)(n0 + row) * 256 + k0 + sg * 8, b_lds + r0 * 32);
    }
    __syncthreads();
    short8 af[4], bf[4];
    #pragma unroll
    for (int t = 0; t < 4; ++t) {
      const int ra = wm + t * 16 + l15;
      af[t] = *(const short8*)(a_lds + ra * 32 + ((l4 ^ (ra & 3)) * 8));
      const int rb = wn + t * 16 + l15;
      bf[t] = *(const short8*)(b_lds + rb * 32 + ((l4 ^ (rb & 3)) * 8));
    }
    #pragma unroll
    for (int mt = 0; mt < 4; ++mt)
      #pragma unroll
      for (int nt = 0; nt < 4; ++nt) acc[mt][nt] = MFMA16(af[mt], bf[nt], acc[mt][nt]);
  }

  const bool isQ = n0 < 256;
  u16* out = isQ ? Qs : Ks;
  const float* bias = isQ ? bq : bk;
  const float scale = isQ ? 0.0625f : 1.0f;
  const int nc0 = n0 & 255;
  float bv[4];
  #pragma unroll
  for (int nt = 0; nt < 4; ++nt) bv[nt] = bias[nc0 + wn + nt * 16 + l15];
  #pragma unroll
  for (int mt = 0; mt < 4; ++mt)
    #pragma unroll
    for (int nt = 0; nt < 4; ++nt)
      #pragma unroll
      for (int r = 0; r < 4; ++r) {
        const int row = m0 + wm + mt * 16 + l4 * 4 + r;
        const int col = nc0 + wn + nt * 16 + l15;
        out[(long)row * 256 + col] = f2bf((acc[mt][nt][r] + bv[nt]) * scale);
      }
}

// ---------------------------------------------------------------------------
// attention R5: R1 compute (wave quadrants, 64-VGPR Q) + pipelined staging.
// Per tile: [vmcnt(8)+bar: K(st) landed] S-MFMA -> exp -> P write ->
// [lgkm+bar: P visible, k_lds readers done] issue K(st+1) ->
// [vmcnt(8)+bar: V(st) landed] PV-MFMA -> [lgkm+bar: v/p readers done] ->
// issue V(st+1).  16 GLLs outstanding at each wait; K/V alternate old/new.
__global__ __launch_bounds__(256, 2) void attn_kernel(
    const u16* __restrict__ Qs, const u16* __restrict__ Ks,
    const u16* __restrict__ Vt, u16* __restrict__ Z) {
  __shared__ u16 k_lds[16384];    // 64 x 256 (granule-swizzled), 32 KiB
  __shared__ u16 v_lds[16384];    // 256 x 64 (granule-swizzled), 32 KiB
  __shared__ u16 p_lds[64 * 72];  // [q][s], pad 8 -> 9 KiB (separate buffer)
  __shared__ float l_buf[128];

  const int tid = threadIdx.x, w = tid >> 6, l = tid & 63;
  const int l15 = l & 15, l4 = l >> 4;
  const int bid = blockIdx.x;
  const int batch = bid & 7;   // bid%8: one batch per XCD if XCD = bid%8
  const int qt = bid >> 3;
  const int wrow0 = (w >> 1) * 32, wcolS = (w & 1) * 32, wcolO = (w & 1) * 128;
  const long qrow_base = (long)batch * 4096 + qt * 64;

  const u16* kbase = Ks + (long)batch * 4096 * 256;
  const u16* vbase = Vt + (long)batch * 256 * 4096;

  // Q fragments in registers: rows wrow0..wrow0+31, all 256 k. 64 VGPR.
  short8 qf[2][8];
  {
    const u16* qp = Qs + (qrow_base + wrow0) * 256;
    #pragma unroll
    for (int mt = 0; mt < 2; ++mt)
      #pragma unroll
      for (int ks = 0; ks < 8; ++ks)
        qf[mt][ks] = *(const short8*)(qp + (mt * 16 + l15) * 256 + ks * 32 + l4 * 8);
  }

  // per-wave GLL staging addresses (R1 layout, j-invariant swizzles)
  const int rowk = 2 * w + (l >> 5);
  const int sgk = (l & 31) ^ (rowk & 7);
  const int cvv = 8 * w + (l >> 3);
  const int sgv = (l & 7) ^ (cvv & 7);

  f32x4 o_acc[2][8];
  #pragma unroll
  for (int mt = 0; mt < 2; ++mt)
    #pragma unroll
    for (int nt = 0; nt < 8; ++nt) o_acc[mt][nt] = (f32x4)0.f;
  float rs[2][4] = {{0.f, 0.f, 0.f, 0.f}, {0.f, 0.f, 0.f, 0.f}};

  // prologue: issue K(0) then V(0) -> 16 outstanding (K older, V newer)
  #pragma unroll
  for (int j = 0; j < 8; ++j) {
    const int r0 = (j * 4 + w) * 2;
    GLL16(kbase + (long)(r0 + (l >> 5)) * 256 + sgk * 8, k_lds + r0 * 256);
  }
  #pragma unroll
  for (int j = 0; j < 8; ++j) {
    const int c0 = (j * 4 + w) * 8;
    GLL16(vbase + (long)(c0 + (l >> 3)) * 4096 + sgv * 8, v_lds + c0 * 64);
  }

  for (int st = 0; st < 64; ++st) {
    const int snn = ((st + 1) & 63) * 64;  // next tile (wraps at 63: harmless)

    BAR_VM8();  // K(st) landed block-wide (V(st) may still fly)

    // S = Q K^T (quadrant 32x32), Q prescaled by 1/16
    f32x4 sacc[2][2];
    #pragma unroll
    for (int i = 0; i < 2; ++i)
      #pragma unroll
      for (int j = 0; j < 2; ++j) sacc[i][j] = (f32x4)0.f;
    #pragma unroll
    for (int ks = 0; ks < 8; ++ks) {
      short8 kf[2];
      #pragma unroll
      for (int nt = 0; nt < 2; ++nt) {
        const int row = wcolS + nt * 16 + l15;
        const int gk = (ks * 4 + l4) ^ (row & 7);
        kf[nt] = *(const short8*)(k_lds + row * 256 + gk * 8);
      }
      #pragma unroll
      for (int mt = 0; mt < 2; ++mt)
        #pragma unroll
        for (int nt = 0; nt < 2; ++nt) sacc[mt][nt] = MFMA16(qf[mt][ks], kf[nt], sacc[mt][nt]);
    }

    // P = exp(S); rowsums; P -> p_lds (separate buffer)
    #pragma unroll
    for (int mt = 0; mt < 2; ++mt)
      #pragma unroll
      for (int nt = 0; nt < 2; ++nt)
        #pragma unroll
        for (int r = 0; r < 4; ++r) {
          float p = __expf(sacc[mt][nt][r]);
          rs[mt][r] += p;
          const int prow = wrow0 + mt * 16 + l4 * 4 + r;
          const int pcol = wcolS + nt * 16 + l15;
          p_lds[prow * 72 + pcol] = f2bf(p);
        }

    BAR_LGKM();  // P visible; all waves past their k_lds reads

    // issue K(st+1): drains during PV(st)
    #pragma unroll
    for (int j = 0; j < 8; ++j) {
      const int r0 = (j * 4 + w) * 2;
      GLL16(kbase + (long)(snn + r0 + (l >> 5)) * 256 + sgk * 8, k_lds + r0 * 256);
    }

    BAR_VM8();  // V(st) landed block-wide (K(st+1) still fly)

    // O += P V
    #pragma unroll
    for (int ks2 = 0; ks2 < 2; ++ks2) {
      short8 pa[2];
      #pragma unroll
      for (int mt = 0; mt < 2; ++mt)
        pa[mt] = *(const short8*)(p_lds + (wrow0 + mt * 16 + l15) * 72 + ks2 * 32 + l4 * 8);
      #pragma unroll
      for (int nt = 0; nt < 8; ++nt) {
        const int c = wcolO + nt * 16 + l15;
        const int gv = (ks2 * 4 + l4) ^ (c & 7);
        short8 vb = *(const short8*)(v_lds + c * 64 + gv * 8);
        #pragma unroll
        for (int mt = 0; mt < 2; ++mt) o_acc[mt][nt] = MFMA16(pa[mt], vb, o_acc[mt][nt]);
      }
    }

    BAR_LGKM();  // all waves past v_lds / p_lds reads

    // issue V(st+1): drains during S(st+1)
    #pragma unroll
    for (int j = 0; j < 8; ++j) {
      const int c0 = (j * 4 + w) * 8;
      GLL16(vbase + (long)(c0 + (l >> 3)) * 4096 + snn + sgv * 8, v_lds + c0 * 64);
    }
  }

  // rowsum: reduce across the 16 lanes of each quad-group
  #pragma unroll
  for (int mt = 0; mt < 2; ++mt)
    #pragma unroll
    for (int r = 0; r < 4; ++r) {
      float v = rs[mt][r];
      v += __shfl_xor(v, 1); v += __shfl_xor(v, 2);
      v += __shfl_xor(v, 4); v += __shfl_xor(v, 8);
      rs[mt][r] = v;
    }
  if (l15 == 0) {
    #pragma unroll
    for (int mt = 0; mt < 2; ++mt)
      #pragma unroll
      for (int r = 0; r < 4; ++r)
        l_buf[(w & 1) * 64 + wrow0 + mt * 16 + l4 * 4 + r] = rs[mt][r];
  }
  __syncthreads();  // (also drains the wrapped prefetch -- once, harmless)

  // normalize + store Z (B,T,C) bf16
  #pragma unroll
  for (int mt = 0; mt < 2; ++mt) {
    float inv[4];
    #pragma unroll
    for (int r = 0; r < 4; ++r) {
      const int row = wrow0 + mt * 16 + l4 * 4 + r;
      inv[r] = 1.f / (l_buf[row] + l_buf[64 + row]);
    }
    #pragma unroll
    for (int nt = 0; nt < 8; ++nt) {
      const int col = wcolO + nt * 16 + l15;
      #pragma unroll
      for (int r = 0; r < 4; ++r) {
        const long row = qrow_base + wrow0 + mt * 16 + l4 * 4 + r;
        Z[row * 256 + col] = f2bf(o_acc[mt][nt][r] * inv[r]);
      }
    }
  }
}

// ---------------------------------------------------------------------------
extern "C" void kernel_launch(void* const* d_in, const int* in_sizes, int n_in,
                              void* d_out, int out_size, void* d_ws, size_t ws_size,
                              hipStream_t stream) {
  (void)in_sizes; (void)n_in; (void)out_size; (void)ws_size;
  const float* x     = (const float*)d_in[0];
  const float* gamma = (const float*)d_in[1];
  const float* beta  = (const float*)d_in[2];
  const float* wq    = (const float*)d_in[3];
  const float* bq    = (const float*)d_in[4];
  const float* wk    = (const float*)d_in[5];
  const float* bk    = (const float*)d_in[6];
  const float* wv    = (const float*)d_in[7];
  const float* bv    = (const float*)d_in[8];
  const float* wp    = (const float*)d_in[9];
  const float* bp    = (const float*)d_in[10];
  float* out = (float*)d_out;

  char* ws = (char*)d_ws;
  u16*    wb    = (u16*)(ws);                  // 4 x 65536 bf16 (wq|wk|wv|wp)
  float2* stats = (float2*)(ws + 524288);      // 256 x float2
  u16*    h_t   = (u16*)(ws + 526336);         // (B,T,C) bf16
  u16*    Qs    = (u16*)(ws + 17303552);       // (B,T,C) bf16, prescaled /16
  u16*    Ks    = (u16*)(ws + 34080768);       // (B,T,C) bf16
  u16*    Vt    = (u16*)(ws + 50857984);       // (B,C,T) bf16
  u16*    Zb    = (u16*)(ws + 67635200);       // (B,T,C) bf16

  conv_w<<<dim3(64, 4), dim3(256), 0, stream>>>(wq, wk, wv, wp, wb);
  gn_stats<<<dim3(256), dim3(256), 0, stream>>>(x, stats);
  gn_apply<<<dim3(64, 4, 8), dim3(256), 0, stream>>>(x, stats, gamma, beta, h_t);

  const long sB = 4096L * 256L, sO = 256L * 4096L;
  // Q+K merged: (32768x256) x (512x256)^T, one pass over h_t
  gemm_qk<<<dim3(4, 256), dim3(256), 0, stream>>>(h_t, wb, bq, bk, Qs, Ks);
  // V^T per batch: (256x256) x (4096x256)^T -> (B,C,T)
  gemm_bt<true, false><<<dim3(32, 2, 8), dim3(256), 0, stream>>>(
      wb + 2 * 65536, 0L, h_t, sB, bv, 1.0f, Vt, nullptr, nullptr, sO, 4096);

  attn_kernel<<<dim3(512), dim3(256), 0, stream>>>(Qs, Ks, Vt, Zb);

  // proj per batch + bias + residual -> fp32 out (B,C,T)
  gemm_bt<true, true><<<dim3(32, 2, 8), dim3(256), 0, stream>>>(
      wb + 3 * 65536, 0L, Zb, sB, bp, 1.0f, nullptr, out, x, sO, 4096);
}

// Round 6
// 295.627 us; speedup vs baseline: 2.4370x; 1.0368x over previous
//
#include <hip/hip_runtime.h>

// ---------------------------------------------------------------------------
// SelfAttention (GN -> QKV 1x1 -> softmax(QK^T/16)V -> proj 1x1 + residual)
// B=8, C=256, GROUPS=32, H=W=64 -> T=4096. fp32 in/out.
//
// R6 attention = R5 (quadrant split + pipelined GLL, 183.9 us) +
//   (1) S^T orientation: MFMA(kf, qf) -> D[s][q]; lane holds 4 consecutive
//       s at fixed q -> P written as 4x ds_write_b64 (was 16x conflicted
//       ds_write_b16; the 1.05e7 conflicts were these).  PV phase unchanged.
//   (2) fp8 e4m3 Q,K (stored as Q/4, K/4 -> scores/16 preserved): S-phase
//       mfma_f32_16x16x32_fp8_fp8 (same rate as bf16), kf reads b64 (half
//       bytes), K staging 16 KB (4 GLLs).  V and P remain bf16.
// ---------------------------------------------------------------------------

typedef unsigned short u16;
typedef unsigned char u8;
typedef __attribute__((ext_vector_type(8))) short short8;   // 8 bf16 = 4 VGPR
typedef __attribute__((ext_vector_type(4))) float f32x4;    // 16x16 C/D

#define MFMA16(a, b, c) __builtin_amdgcn_mfma_f32_16x16x32_bf16((a), (b), (c), 0, 0, 0)
#define MFMA16F8(a, b, c) __builtin_amdgcn_mfma_f32_16x16x32_fp8_fp8((a), (b), (c), 0, 0, 0)

#define GLL16(g, l)                                                            \
  __builtin_amdgcn_global_load_lds(                                            \
      (const __attribute__((address_space(1))) void*)(g),                      \
      (__attribute__((address_space(3))) void*)(l), 16, 0, 0)

// pipeline barriers: never wait vmcnt(0); K staging = 4 GLLs, V = 8 GLLs
#define BAR_VM8()  asm volatile("s_waitcnt vmcnt(8)\n\ts_barrier" ::: "memory")
#define BAR_VM4()  asm volatile("s_waitcnt vmcnt(4)\n\ts_barrier" ::: "memory")
#define BAR_LGKM() asm volatile("s_waitcnt lgkmcnt(0)\n\ts_barrier" ::: "memory")

__device__ __forceinline__ u16 f2bf(float f) {  // RNE fp32 -> bf16 bits
  union { float f; unsigned u; } v; v.f = f;
  unsigned u = v.u;
  return (u16)((u + 0x7FFFu + ((u >> 16) & 1u)) >> 16);
}

__device__ __forceinline__ u8 f2fp8(float f) {  // fp32 -> OCP e4m3 byte
  int p = __builtin_amdgcn_cvt_pk_fp8_f32(f, f, 0, false);
  return (u8)(p & 0xff);
}

// ---------------------------------------------------------------------------
// 0) weights fp32 -> bf16 (wq|wk|wv|wp contiguous: 4 x 65536)
__global__ __launch_bounds__(256) void conv_w(const float* __restrict__ s0,
                                              const float* __restrict__ s1,
                                              const float* __restrict__ s2,
                                              const float* __restrict__ s3,
                                              u16* __restrict__ dst) {
  const int m = blockIdx.y;
  const float* s = (m == 0) ? s0 : (m == 1) ? s1 : (m == 2) ? s2 : s3;
  const int i = (blockIdx.x * 256 + threadIdx.x) * 4;
  float4 v = *(const float4*)(s + i);
  u16* d = dst + m * 65536 + i;
  d[0] = f2bf(v.x); d[1] = f2bf(v.y); d[2] = f2bf(v.z); d[3] = f2bf(v.w);
}

// ---------------------------------------------------------------------------
// 1) GroupNorm stats: one block per (b,g) contiguous 32768-float chunk.
__global__ __launch_bounds__(256) void gn_stats(const float* __restrict__ x,
                                                float2* __restrict__ stats) {
  const int bg = blockIdx.x;
  const float* p = x + (long)bg * 32768;
  const int tid = threadIdx.x;
  float s = 0.f, ss = 0.f;
  #pragma unroll 8
  for (int i = 0; i < 32; ++i) {
    float4 v = *(const float4*)(p + tid * 4 + i * 1024);
    s  += v.x + v.y + v.z + v.w;
    ss += v.x * v.x + v.y * v.y + v.z * v.z + v.w * v.w;
  }
  for (int off = 32; off; off >>= 1) {
    s  += __shfl_down(s, off);
    ss += __shfl_down(ss, off);
  }
  __shared__ float2 red[4];
  if ((tid & 63) == 0) red[tid >> 6] = make_float2(s, ss);
  __syncthreads();
  if (tid == 0) {
    float S  = red[0].x + red[1].x + red[2].x + red[3].x;
    float SS = red[0].y + red[1].y + red[2].y + red[3].y;
    float mean = S * (1.f / 32768.f);
    float var  = SS * (1.f / 32768.f) - mean * mean;
    stats[bg] = make_float2(mean, rsqrtf(var + 1e-5f));
  }
}

// ---------------------------------------------------------------------------
// 2) normalize + transpose: x (B,C,T) f32 -> h_t (B,T,C) bf16.
__global__ __launch_bounds__(256) void gn_apply(const float* __restrict__ x,
                                                const float2* __restrict__ stats,
                                                const float* __restrict__ gamma,
                                                const float* __restrict__ beta,
                                                u16* __restrict__ h_t) {
  __shared__ float tile[64][65];
  const int tid = threadIdx.x;
  const int b = blockIdx.z, c0 = blockIdx.y * 64, t0 = blockIdx.x * 64;
  {
    const int ci = tid >> 2, tj0 = (tid & 3) * 16;
    const int c = c0 + ci;
    float2 st = stats[b * 32 + (c >> 3)];
    float gm = gamma[c] * st.y;
    float bt = beta[c] - st.x * gm;
    const float* xp = x + ((long)(b * 256 + c) * 4096 + t0 + tj0);
    #pragma unroll
    for (int i = 0; i < 4; ++i) {
      float4 v = *(const float4*)(xp + i * 4);
      tile[ci][tj0 + i * 4 + 0] = v.x * gm + bt;
      tile[ci][tj0 + i * 4 + 1] = v.y * gm + bt;
      tile[ci][tj0 + i * 4 + 2] = v.z * gm + bt;
      tile[ci][tj0 + i * 4 + 3] = v.w * gm + bt;
    }
  }
  __syncthreads();
  {
    const int tj = tid >> 2, ci0 = (tid & 3) * 16;
    u16* hp = h_t + ((long)(b * 4096 + t0 + tj) * 256 + c0 + ci0);
    short8 v0, v1;
    #pragma unroll
    for (int i = 0; i < 8; ++i) v0[i] = (short)f2bf(tile[ci0 + i][tj]);
    #pragma unroll
    for (int i = 0; i < 8; ++i) v1[i] = (short)f2bf(tile[ci0 + 8 + i][tj]);
    *(short8*)hp = v0;
    *(short8*)(hp + 8) = v1;
  }
}

// ---------------------------------------------------------------------------
// gemm_bt (128x128 tile, BK=32, 4 waves, XOR granule swizzle).
template <bool ROW_BIAS, bool RESID>
__global__ __launch_bounds__(256, 2) void gemm_bt(
    const u16* __restrict__ A, long strideAz, const u16* __restrict__ B,
    long strideBz, const float* __restrict__ bias, float scale,
    u16* __restrict__ outb, float* __restrict__ outf,
    const float* __restrict__ resid, long strideOz, int N) {
  __shared__ u16 a_lds[128 * 32];
  __shared__ u16 b_lds[128 * 32];
  const int tid = threadIdx.x, w = tid >> 6, l = tid & 63;
  const int l15 = l & 15, l4 = l >> 4;
  const int bz = blockIdx.z;
  A += bz * strideAz;
  B += bz * strideBz;
  const long obase = (long)bz * strideOz;
  const int m0 = blockIdx.y * 128, n0 = blockIdx.x * 128;
  const int wm = (w >> 1) * 64, wn = (w & 1) * 64;

  f32x4 acc[4][4];
  #pragma unroll
  for (int i = 0; i < 4; ++i)
    #pragma unroll
    for (int j = 0; j < 4; ++j) acc[i][j] = (f32x4)0.f;

  for (int kt = 0; kt < 8; ++kt) {
    const int k0 = kt * 32;
    __syncthreads();
    #pragma unroll
    for (int j = 0; j < 2; ++j) {
      const int r0 = (w * 2 + j) * 16;
      const int row = r0 + (l >> 2);
      const int sg = (l & 3) ^ (row & 3);
      GLL16(A + (long)(m0 + row) * 256 + k0 + sg * 8, a_lds + r0 * 32);
      GLL16(B + (long)(n0 + row) * 256 + k0 + sg * 8, b_lds + r0 * 32);
    }
    __syncthreads();
    short8 af[4], bf[4];
    #pragma unroll
    for (int t = 0; t < 4; ++t) {
      const int ra = wm + t * 16 + l15;
      af[t] = *(const short8*)(a_lds + ra * 32 + ((l4 ^ (ra & 3)) * 8));
      const int rb = wn + t * 16 + l15;
      bf[t] = *(const short8*)(b_lds + rb * 32 + ((l4 ^ (rb & 3)) * 8));
    }
    #pragma unroll
    for (int mt = 0; mt < 4; ++mt)
      #pragma unroll
      for (int nt = 0; nt < 4; ++nt) acc[mt][nt] = MFMA16(af[mt], bf[nt], acc[mt][nt]);
  }

  if (!ROW_BIAS) {
    float bv[4];
    #pragma unroll
    for (int nt = 0; nt < 4; ++nt) bv[nt] = bias[n0 + wn + nt * 16 + l15];
    #pragma unroll
    for (int mt = 0; mt < 4; ++mt)
      #pragma unroll
      for (int nt = 0; nt < 4; ++nt)
        #pragma unroll
        for (int r = 0; r < 4; ++r) {
          const int row = m0 + wm + mt * 16 + l4 * 4 + r;
          const int col = n0 + wn + nt * 16 + l15;
          outb[obase + (long)row * N + col] = f2bf((acc[mt][nt][r] + bv[nt]) * scale);
        }
  } else {
    float bm[4][4];
    #pragma unroll
    for (int mt = 0; mt < 4; ++mt)
      #pragma unroll
      for (int r = 0; r < 4; ++r) bm[mt][r] = bias[m0 + wm + mt * 16 + l4 * 4 + r];
    #pragma unroll
    for (int mt = 0; mt < 4; ++mt)
      #pragma unroll
      for (int nt = 0; nt < 4; ++nt)
        #pragma unroll
        for (int r = 0; r < 4; ++r) {
          const int row = m0 + wm + mt * 16 + l4 * 4 + r;
          const int col = n0 + wn + nt * 16 + l15;
          const long idx = obase + (long)row * N + col;
          float v = acc[mt][nt][r] + bm[mt][r];
          if (RESID) outf[idx] = v + resid[idx];
          else       outb[idx] = f2bf(v);
        }
  }
}

// ---------------------------------------------------------------------------
// merged Q+K projection -> fp8 e4m3 outputs, scaled by 1/4 each (after bias)
// so that Qs8.Ks8 = score/16.  cols 0-255 -> Qs8 (bias bq), 256-511 -> Ks8.
__global__ __launch_bounds__(256, 2) void gemm_qk(
    const u16* __restrict__ A, const u16* __restrict__ Bw,
    const float* __restrict__ bq, const float* __restrict__ bk,
    u8* __restrict__ Qs8, u8* __restrict__ Ks8) {
  __shared__ u16 a_lds[128 * 32];
  __shared__ u16 b_lds[128 * 32];
  const int tid = threadIdx.x, w = tid >> 6, l = tid & 63;
  const int l15 = l & 15, l4 = l >> 4;
  const int m0 = blockIdx.y * 128, n0 = blockIdx.x * 128;
  const int wm = (w >> 1) * 64, wn = (w & 1) * 64;

  f32x4 acc[4][4];
  #pragma unroll
  for (int i = 0; i < 4; ++i)
    #pragma unroll
    for (int j = 0; j < 4; ++j) acc[i][j] = (f32x4)0.f;

  for (int kt = 0; kt < 8; ++kt) {
    const int k0 = kt * 32;
    __syncthreads();
    #pragma unroll
    for (int j = 0; j < 2; ++j) {
      const int r0 = (w * 2 + j) * 16;
      const int row = r0 + (l >> 2);
      const int sg = (l & 3) ^ (row & 3);
      GLL16(A + (long)(m0 + row) * 256 + k0 + sg * 8, a_lds + r0 * 32);
      GLL16(Bw + (long)(n0 + row) * 256 + k0 + sg * 8, b_lds + r0 * 32);
    }
    __syncthreads();
    short8 af[4], bf[4];
    #pragma unroll
    for (int t = 0; t < 4; ++t) {
      const int ra = wm + t * 16 + l15;
      af[t] = *(const short8*)(a_lds + ra * 32 + ((l4 ^ (ra & 3)) * 8));
      const int rb = wn + t * 16 + l15;
      bf[t] = *(const short8*)(b_lds + rb * 32 + ((l4 ^ (rb & 3)) * 8));
    }
    #pragma unroll
    for (int mt = 0; mt < 4; ++mt)
      #pragma unroll
      for (int nt = 0; nt < 4; ++nt) acc[mt][nt] = MFMA16(af[mt], bf[nt], acc[mt][nt]);
  }

  const bool isQ = n0 < 256;
  u8* out = isQ ? Qs8 : Ks8;
  const float* bias = isQ ? bq : bk;
  const int nc0 = n0 & 255;
  float bv[4];
  #pragma unroll
  for (int nt = 0; nt < 4; ++nt) bv[nt] = bias[nc0 + wn + nt * 16 + l15];
  #pragma unroll
  for (int mt = 0; mt < 4; ++mt)
    #pragma unroll
    for (int nt = 0; nt < 4; ++nt)
      #pragma unroll
      for (int r = 0; r < 4; ++r) {
        const int row = m0 + wm + mt * 16 + l4 * 4 + r;
        const int col = nc0 + wn + nt * 16 + l15;
        out[(long)row * 256 + col] = f2fp8((acc[mt][nt][r] + bv[nt]) * 0.25f);
      }
}

// ---------------------------------------------------------------------------
// attention R6: quadrant split (R5), S^T orientation, fp8 Q/K.
// Wave w: S^T quadrant s in [ws0,+32), q in [wq0,+32); ws0=(w&1)*32,
// wq0=(w>>1)*32.  PV: q in [wq0,+32) x c in [(w&1)*128,+128)  (= R5).
// k_lds8: 64 s-rows x 256 B fp8, 16B-granule XOR-16 swizzle.
// Pipeline: [vm8] S -> exp -> P(b64) -> [lgkm] issue K+1 -> [vm4] PV ->
// [lgkm] issue V+1.  K = 4 GLLs, V = 8 GLLs; 12 outstanding at each wait.
__global__ __launch_bounds__(256, 2) void attn_kernel(
    const u8* __restrict__ Qs8, const u8* __restrict__ Ks8,
    const u16* __restrict__ Vt, u16* __restrict__ Z) {
  __shared__ u8  k_lds8[16384];   // 64 x 256 B (granule-swizzled), 16 KiB
  __shared__ u16 v_lds[16384];    // 256 x 64 bf16 (granule-swizzled), 32 KiB
  __shared__ u16 p_lds[64 * 72];  // [q][s] bf16, pad 8 -> 9 KiB
  __shared__ float l_red[256];    // [wave][q] rowsum partials -> inv totals

  const int tid = threadIdx.x, w = tid >> 6, l = tid & 63;
  const int l15 = l & 15, l4 = l >> 4;
  const int bid = blockIdx.x;
  const int batch = bid & 7;   // bid%8: one batch per XCD if XCD = bid%8
  const int qt = bid >> 3;
  const int ws0 = (w & 1) * 32, wq0 = (w >> 1) * 32, wcolO = (w & 1) * 128;
  const long qrow_base = (long)batch * 4096 + qt * 64;

  const u8*  kbase = Ks8 + (long)batch * 4096 * 256;
  const u16* vbase = Vt + (long)batch * 256 * 4096;

  // Q fragments (B-operand of S^T): rows wq0..+31, fp8, 32 VGPR.
  long qf[2][8];
  {
    const u8* qp = Qs8 + (qrow_base + wq0) * 256;
    #pragma unroll
    for (int qt2 = 0; qt2 < 2; ++qt2)
      #pragma unroll
      for (int ks = 0; ks < 8; ++ks)
        qf[qt2][ks] = *(const long*)(qp + (qt2 * 16 + l15) * 256 + ks * 32 + l4 * 8);
  }

  // V staging addresses (R5 layout, j-invariant swizzle)
  const int cvv = 8 * w + (l >> 3);
  const int sgv = (l & 7) ^ (cvv & 7);

  f32x4 o_acc[2][8];
  #pragma unroll
  for (int mt = 0; mt < 2; ++mt)
    #pragma unroll
    for (int nt = 0; nt < 8; ++nt) o_acc[mt][nt] = (f32x4)0.f;
  float rs2[2] = {0.f, 0.f};

  // prologue: issue K(0) [4 GLL] then V(0) [8 GLL] -> 12 outstanding
  #pragma unroll
  for (int j = 0; j < 4; ++j) {
    const int r0 = (j * 4 + w) * 4;
    const int row = r0 + (l >> 4);
    const int g = (l & 15) ^ (row & 15);
    GLL16(kbase + (long)row * 256 + g * 16, k_lds8 + r0 * 256);
  }
  #pragma unroll
  for (int j = 0; j < 8; ++j) {
    const int c0 = (j * 4 + w) * 8;
    GLL16(vbase + (long)(c0 + (l >> 3)) * 4096 + sgv * 8, v_lds + c0 * 64);
  }

  for (int st = 0; st < 64; ++st) {
    const int snn = ((st + 1) & 63) * 64;  // next tile (wrap at 63: harmless)

    BAR_VM8();  // K(st) landed block-wide (V(st) 8 still in flight)

    // S^T quadrant: A = K[s][k] fp8 (m = s), B = qf (n = q)
    f32x4 sacc[2][2];
    #pragma unroll
    for (int i = 0; i < 2; ++i)
      #pragma unroll
      for (int j = 0; j < 2; ++j) sacc[i][j] = (f32x4)0.f;
    #pragma unroll
    for (int ks = 0; ks < 8; ++ks) {
      long kf[2];
      #pragma unroll
      for (int st2 = 0; st2 < 2; ++st2) {
        const int row = ws0 + st2 * 16 + l15;
        const int g = (ks * 2 + (l4 >> 1)) ^ l15;  // row&15 == l15
        kf[st2] = *(const long*)(k_lds8 + row * 256 + g * 16 + (l4 & 1) * 8);
      }
      #pragma unroll
      for (int st2 = 0; st2 < 2; ++st2)
        #pragma unroll
        for (int qt2 = 0; qt2 < 2; ++qt2)
          sacc[st2][qt2] = MFMA16F8(kf[st2], qf[qt2][ks], sacc[st2][qt2]);
    }

    // exp + rowsum + P write: lane holds s = ws0+st2*16+l4*4+r, q = wq0+qt2*16+l15
    #pragma unroll
    for (int st2 = 0; st2 < 2; ++st2)
      #pragma unroll
      for (int qt2 = 0; qt2 < 2; ++qt2) {
        float e0 = __expf(sacc[st2][qt2][0]), e1 = __expf(sacc[st2][qt2][1]);
        float e2 = __expf(sacc[st2][qt2][2]), e3 = __expf(sacc[st2][qt2][3]);
        rs2[qt2] += (e0 + e1) + (e2 + e3);
        ushort4 pk = {f2bf(e0), f2bf(e1), f2bf(e2), f2bf(e3)};
        *(ushort4*)(p_lds + (wq0 + qt2 * 16 + l15) * 72 + ws0 + st2 * 16 + l4 * 4) = pk;
      }

    BAR_LGKM();  // P visible; all waves past their k_lds8 reads

    // issue K(st+1): drains during PV(st)
    #pragma unroll
    for (int j = 0; j < 4; ++j) {
      const int r0 = (j * 4 + w) * 4;
      const int row = r0 + (l >> 4);
      const int g = (l & 15) ^ (row & 15);
      GLL16(kbase + (long)(snn + row) * 256 + g * 16, k_lds8 + r0 * 256);
    }

    BAR_VM4();  // V(st) landed block-wide (K(st+1) 4 still in flight)

    // O += P V  (unchanged R5 pattern; wq0 == R5's wrow0)
    #pragma unroll
    for (int ks2 = 0; ks2 < 2; ++ks2) {
      short8 pa[2];
      #pragma unroll
      for (int mt = 0; mt < 2; ++mt)
        pa[mt] = *(const short8*)(p_lds + (wq0 + mt * 16 + l15) * 72 + ks2 * 32 + l4 * 8);
      #pragma unroll
      for (int nt = 0; nt < 8; ++nt) {
        const int c = wcolO + nt * 16 + l15;
        const int gv = (ks2 * 4 + l4) ^ (c & 7);
        short8 vb = *(const short8*)(v_lds + c * 64 + gv * 8);
        #pragma unroll
        for (int mt = 0; mt < 2; ++mt) o_acc[mt][nt] = MFMA16(pa[mt], vb, o_acc[mt][nt]);
      }
    }

    BAR_LGKM();  // all waves past v_lds / p_lds reads

    // issue V(st+1): drains during S(st+1)
    #pragma unroll
    for (int j = 0; j < 8; ++j) {
      const int c0 = (j * 4 + w) * 8;
      GLL16(vbase + (long)(c0 + (l >> 3)) * 4096 + snn + sgv * 8, v_lds + c0 * 64);
    }
  }

  // rowsums: lane (qt2,l15) holds partial over its 8 s; reduce over l4, then
  // across the wave pair (same wq0, different ws0) via l_red.
  #pragma unroll
  for (int qt2 = 0; qt2 < 2; ++qt2) {
    float v = rs2[qt2];
    v += __shfl_xor(v, 16);
    v += __shfl_xor(v, 32);
    if (l4 == 0) l_red[w * 64 + wq0 + qt2 * 16 + l15] = v;
  }
  __syncthreads();
  if (tid < 64) {
    const int w0 = (tid >> 5) * 2;  // q<32: waves 0+1; q>=32: waves 2+3
    float t = l_red[w0 * 64 + tid] + l_red[(w0 + 1) * 64 + tid];
    l_red[tid] = 1.f / t;
  }
  __syncthreads();

  // normalize + store Z (B,T,C) bf16
  #pragma unroll
  for (int mt = 0; mt < 2; ++mt) {
    float inv[4];
    #pragma unroll
    for (int r = 0; r < 4; ++r) inv[r] = l_red[wq0 + mt * 16 + l4 * 4 + r];
    #pragma unroll
    for (int nt = 0; nt < 8; ++nt) {
      const int col = wcolO + nt * 16 + l15;
      #pragma unroll
      for (int r = 0; r < 4; ++r) {
        const long row = qrow_base + wq0 + mt * 16 + l4 * 4 + r;
        Z[row * 256 + col] = f2bf(o_acc[mt][nt][r] * inv[r]);
      }
    }
  }
}

// ---------------------------------------------------------------------------
extern "C" void kernel_launch(void* const* d_in, const int* in_sizes, int n_in,
                              void* d_out, int out_size, void* d_ws, size_t ws_size,
                              hipStream_t stream) {
  (void)in_sizes; (void)n_in; (void)out_size; (void)ws_size;
  const float* x     = (const float*)d_in[0];
  const float* gamma = (const float*)d_in[1];
  const float* beta  = (const float*)d_in[2];
  const float* wq    = (const float*)d_in[3];
  const float* bq    = (const float*)d_in[4];
  const float* wk    = (const float*)d_in[5];
  const float* bk    = (const float*)d_in[6];
  const float* wv    = (const float*)d_in[7];
  const float* bv    = (const float*)d_in[8];
  const float* wp    = (const float*)d_in[9];
  const float* bp    = (const float*)d_in[10];
  float* out = (float*)d_out;

  char* ws = (char*)d_ws;
  u16*    wb    = (u16*)(ws);                  // 4 x 65536 bf16 (wq|wk|wv|wp)
  float2* stats = (float2*)(ws + 524288);      // 256 x float2
  u16*    h_t   = (u16*)(ws + 526336);         // (B,T,C) bf16, 16 MiB
  u8*     Qs8   = (u8*)(ws + 17303552);        // (B,T,C) fp8 (q/4), 8 MiB
  u8*     Ks8   = (u8*)(ws + 25692160);        // (B,T,C) fp8 (k/4), 8 MiB
  u16*    Vt    = (u16*)(ws + 34080768);       // (B,C,T) bf16, 16 MiB
  u16*    Zb    = (u16*)(ws + 50857984);       // (B,T,C) bf16, 16 MiB

  conv_w<<<dim3(64, 4), dim3(256), 0, stream>>>(wq, wk, wv, wp, wb);
  gn_stats<<<dim3(256), dim3(256), 0, stream>>>(x, stats);
  gn_apply<<<dim3(64, 4, 8), dim3(256), 0, stream>>>(x, stats, gamma, beta, h_t);

  const long sB = 4096L * 256L, sO = 256L * 4096L;
  // Q+K merged: (32768x256) x (512x256)^T -> fp8, one pass over h_t
  gemm_qk<<<dim3(4, 256), dim3(256), 0, stream>>>(h_t, wb, bq, bk, Qs8, Ks8);
  // V^T per batch: (256x256) x (4096x256)^T -> (B,C,T)
  gemm_bt<true, false><<<dim3(32, 2, 8), dim3(256), 0, stream>>>(
      wb + 2 * 65536, 0L, h_t, sB, bv, 1.0f, Vt, nullptr, nullptr, sO, 4096);

  attn_kernel<<<dim3(512), dim3(256), 0, stream>>>(Qs8, Ks8, Vt, Zb);

  // proj per batch + bias + residual -> fp32 out (B,C,T)
  gemm_bt<true, true><<<dim3(32, 2, 8), dim3(256), 0, stream>>>(
      wb + 3 * 65536, 0L, Zb, sB, bp, 1.0f, nullptr, out, x, sO, 4096);
}